// Round 1
// 509.658 us; speedup vs baseline: 1.0567x; 1.0567x over previous
//
#include <hip/hip_runtime.h>
#include <hip/hip_bf16.h>

#define HW 512

typedef __attribute__((ext_vector_type(8))) short bf16x8;
typedef __attribute__((ext_vector_type(4))) float floatx4;

union BFrag { uint2 u2[2]; bf16x8 v; };

static __device__ inline ushort f2bf(float f) {
    __hip_bfloat16 h = __float2bfloat16(f);
    return *(ushort*)&h;
}

// ---------------------------------------------------------------------------
// Implicit-GEMM grouped directional conv on mfma_f32_16x16x32_bf16.
//   M = 16 = NDIR dirs x YPACK output rows (YPACK = 16/NDIR)
//   N = 16 pixels, strided by 4: px = gx0 + r + 4n, phase r = wave id (0..3)
//   K = im2col taps, chunked as (dyu row, 8-consecutive-dx octet), the dx
//       window shifted by -r inside the A fragment so B addresses are
//       phase-independent and 8B-aligned (ds_read_b64).
// A-fragment layout: A[m=lane&15][k=quad*8+j]; B[k=quad*8+j][n=lane&15];
// D: col=lane&15, row=quad*4+reg.  (per cdna_hip_programming.md §3, m89/m120)
//
// R1 changes: three scales fused into ONE kernel (blockIdx.z in [0,36) =
// scale*12 + plane) for counter observability + launch-gap removal; dual
// accumulators (even/odd step) halve the MFMA dependency chain;
// __launch_bounds__(256,4) forces >=4 blocks/CU (VGPR <= 128).
// ---------------------------------------------------------------------------
template<int K, int NDIR, int SUB0, int YPACK, int OCTS, int NSTEP>
__device__ __forceinline__
void conv_body(ushort* __restrict__ s_img,
               const float* __restrict__ img, const float* __restrict__ filt,
               float* __restrict__ out, const int plane)
{
    constexpr int R       = K / 2;
    constexpr int TILE_W  = 64, TILE_H = 32;
    constexpr int NCHAIN  = TILE_H / YPACK;
    constexpr int ROWSP   = (4 * NSTEP - 1) / OCTS + 1;        // staged dyu rows
    constexpr int EXT_Y   = (TILE_H - YPACK) + ROWSP;          // staged image rows
    constexpr int EXT_X   = 4 * 15 + 8 * (OCTS - 1) + 8;       // max col read + 1
    constexpr int SPX     = (EXT_X + 7) & ~7;                  // row stride (mult of 8 elems)
    constexpr int P       = (OCTS == 3) ? 3 : 1;               // addr period in steps
    constexpr int GSTRIDE = (4 * P / OCTS) * SPX;              // elems per step-group

    const int tid   = threadIdx.x;
    const int bx    = blockIdx.x, by = blockIdx.y;
    const int bb    = plane / 3, cc = plane % 3;
    const float* __restrict__ src = img + (size_t)plane * HW * HW;
    const int gx0 = bx * TILE_W, gy0 = by * TILE_H;

    // ---- stage image tile as bf16 (zero-filled OOB; pad cols defined) ----
    constexpr int PAIRS = SPX / 2;
    for (int idx = tid; idx < EXT_Y * PAIRS; idx += 256) {
        const int row = idx / PAIRS;
        const int col = (idx - row * PAIRS) * 2;
        const int gy = gy0 - R + row;
        const int gx = gx0 - R + col;
        float v0 = 0.f, v1 = 0.f;
        if ((unsigned)gy < HW) {
            if ((unsigned)gx       < HW) v0 = src[gy * HW + gx];
            if ((unsigned)(gx + 1) < HW) v1 = src[gy * HW + gx + 1];
        }
        *(uint*)&s_img[row * SPX + col] = ((uint)f2bf(v1) << 16) | (uint)f2bf(v0);
    }

    // ---- build A fragments (filters, phase-shifted, zero-padded) ----
    const int lane = tid & 63;
    const int r    = tid >> 6;                 // wave id = pixel phase
    const int mn   = lane & 15;                // m for A, n for B/D
    const int q    = lane >> 4;                // quad
    const int dirm = mn & (NDIR - 1);
    const int yoffm = mn / NDIR;

    bf16x8 afrag[NSTEP];
    #pragma unroll
    for (int s = 0; s < NSTEP; ++s) {
        #pragma unroll
        for (int j = 0; j < 8; ++j) {
            const int c   = 4 * s + q;
            const int dyu = c / OCTS, o = c - dyu * OCTS;
            const int dy  = dyu - yoffm;
            const int dx  = 8 * o + j - r;
            float fv = 0.f;
            if (dy >= 0 && dy < K && dx >= 0 && dx < K)
                fv = filt[(dirm * K + dy) * K + dx];
            afrag[s][j] = (short)f2bf(fv);
        }
    }
    __syncthreads();

    // per-lane base offsets (elements) for s % P = 0..P-1, chain y = 0
    int base0[P];
    #pragma unroll
    for (int s0 = 0; s0 < P; ++s0) {
        const int c0   = 4 * s0 + q;
        const int dyu0 = c0 / OCTS, o0 = c0 - dyu0 * OCTS;
        base0[s0] = dyu0 * SPX + 8 * o0 + 4 * mn;   // 8B-aligned: SPX%8==0
    }

    const int px = gx0 + r + 4 * mn;

    for (int ch = 0; ch < NCHAIN; ++ch) {
        const int y = ch * YPACK;
        // Dual accumulators: break the serial MFMA->MFMA accumulation chain
        // (compiler cannot reassociate MFMA deps itself).
        floatx4 acc0 = {0.f, 0.f, 0.f, 0.f};
        floatx4 acc1 = {0.f, 0.f, 0.f, 0.f};
        #pragma unroll
        for (int s = 0; s < NSTEP; ++s) {
            const int s0 = s % P, g = s / P;        // compile-time in unrolled loop
            const ushort* p = s_img + (base0[s0] + y * SPX + g * GSTRIDE);
            BFrag b;
            b.u2[0] = *(const uint2*)p;
            b.u2[1] = *(const uint2*)(p + 4);
            if (s & 1)
                acc1 = __builtin_amdgcn_mfma_f32_16x16x32_bf16(afrag[s], b.v, acc1, 0, 0, 0);
            else
                acc0 = __builtin_amdgcn_mfma_f32_16x16x32_bf16(afrag[s], b.v, acc0, 0, 0, 0);
        }
        #pragma unroll
        for (int i = 0; i < 4; ++i) {
            const int mrow = q * 4 + i;
            const int dd = mrow & (NDIR - 1);
            const int yo = mrow / NDIR;
            const int Y  = gy0 + y + yo;
            out[((size_t)(bb * 87 + cc * 29 + SUB0 + dd) * HW + Y) * HW + px] =
                acc0[i] + acc1[i];
        }
    }
}

// Max staged-tile footprint across the three scales (elems):
//   k0: 42*80 = 3360, k1: 46*88 = 4048, k2: 51*88 = 4488.
#define SMEM_ELEMS 4488

__global__ __launch_bounds__(256, 4)
void fused_conv(const float* __restrict__ img,
                const float* __restrict__ f0, const float* __restrict__ f1,
                const float* __restrict__ f2, float* __restrict__ out)
{
    __shared__ __align__(16) ushort s_img[SMEM_ELEMS];
    const int z = blockIdx.z;
    if (z < 12) {
        conv_body<11,  4,  0, 4, 2,  7>(s_img, img, f0, out, z);
    } else if (z < 24) {
        conv_body<15,  8,  4, 2, 3, 12>(s_img, img, f1, out, z - 12);
    } else {
        conv_body<19, 16, 12, 1, 3, 15>(s_img, img, f2, out, z - 24);
    }
}

// ---------------------------------------------------------------------------
// Low channel: 4x4 avg-pool + 4x bilinear upsample (half-pixel, edge clamp).
// ---------------------------------------------------------------------------
__global__ __launch_bounds__(256)
void low_kernel(const float* __restrict__ img, float* __restrict__ out)
{
    __shared__ float s_p[34 * 35];
    const int tid   = threadIdx.x;
    const int bx    = blockIdx.x, by = blockIdx.y;
    const int plane = blockIdx.z;
    const int b     = plane / 3, c = plane % 3;
    const float* __restrict__ src = img + (size_t)plane * HW * HW;
    const int lx0 = bx * 32, ly0 = by * 32;

    for (int idx = tid; idx < 34 * 34; idx += 256) {
        const int r = idx / 34, col = idx % 34;
        const int ly = min(max(ly0 - 1 + r,   0), 127);
        const int lx = min(max(lx0 - 1 + col, 0), 127);
        const float* p = src + (size_t)(ly * 4) * HW + lx * 4;
        float s = 0.f;
        #pragma unroll
        for (int rr = 0; rr < 4; ++rr) {
            const float4 v = *(const float4*)(p + (size_t)rr * HW);
            s += v.x + v.y + v.z + v.w;
        }
        s_p[r * 35 + col] = s * (1.f / 16.f);
    }
    __syncthreads();

    const size_t outbase = (size_t)(b * 87 + c * 29 + 28) * HW * HW;
    for (int k = 0; k < 64; ++k) {
        const int pix = tid + k * 256;
        const int ry = pix >> 7, rx = pix & 127;
        const int gy = ly0 * 4 + ry, gx = lx0 * 4 + rx;
        const float cy = (gy - 1.5f) * 0.25f;
        const float cx = (gx - 1.5f) * 0.25f;
        const int jy = (int)floorf(cy), jx = (int)floorf(cx);
        const float fy = cy - jy, fx = cx - jx;
        const int tyy = jy - (ly0 - 1);
        const int txx = jx - (lx0 - 1);
        const float p00 = s_p[tyy * 35 + txx],       p01 = s_p[tyy * 35 + txx + 1];
        const float p10 = s_p[(tyy + 1) * 35 + txx], p11 = s_p[(tyy + 1) * 35 + txx + 1];
        const float v0 = p00 + fx * (p01 - p00);
        const float v1 = p10 + fx * (p11 - p10);
        out[outbase + (size_t)gy * HW + gx] = v0 + fy * (v1 - v0);
    }
}

extern "C" void kernel_launch(void* const* d_in, const int* in_sizes, int n_in,
                              void* d_out, int out_size, void* d_ws, size_t ws_size,
                              hipStream_t stream)
{
    const float* img = (const float*)d_in[0];
    const float* f0  = (const float*)d_in[1];
    const float* f1  = (const float*)d_in[2];
    const float* f2  = (const float*)d_in[3];
    float* out = (float*)d_out;

    dim3 block(256);
    // z = scale*12 + plane : all three scales in one dispatch.
    fused_conv<<<dim3(HW / 64, HW / 32, 36), block, 0, stream>>>(img, f0, f1, f2, out);
    low_kernel<<<dim3(4, 4, 12), block, 0, stream>>>(img, out);
}